// Round 4
// baseline (1154.090 us; speedup 1.0000x reference)
//
#include <hip/hip_runtime.h>
#include <hip/hip_bf16.h>

#define N_NODES   20000
#define N_EDGES   320000
#define DIM       256
#define N_GRAPHS  64
#define N_CLASSES 10
#define N_PASS    4            // feature chunks of 64 (128 B/row -> 2.5 MB chunk, L2-resident)
// padded CSR capacity: every node rounds its degree up to a multiple of 8
#define CSR_CAP   (N_EDGES + 8 * N_NODES)

typedef short  bf16x8  __attribute__((ext_vector_type(8)));
typedef float  f32x4   __attribute__((ext_vector_type(4)));
typedef ushort ushort8 __attribute__((ext_vector_type(8)));

__device__ __forceinline__ float b2f(ushort u) {
    return __uint_as_float(((unsigned)u) << 16);
}
__device__ __forceinline__ ushort f2b(float f) {
    unsigned u = __float_as_uint(f);
    u += 0x7FFF + ((u >> 16) & 1);   // round-to-nearest-even
    return (ushort)(u >> 16);
}

// ---------------- setup kernels ----------------

__global__ void k_convert_x(const float* __restrict__ x, ushort* __restrict__ xb, int n4) {
    int i = blockIdx.x * blockDim.x + threadIdx.x;
    if (i >= n4) return;
    const float4 v = ((const float4*)x)[i];
    ushort4 o; o.x = f2b(v.x); o.y = f2b(v.y); o.z = f2b(v.z); o.w = f2b(v.w);
    ((ushort4*)xb)[i] = o;
}

// Wt[n*256+k] = bf16(W[k*256+n])
__global__ void k_wt(const float* __restrict__ W, ushort* __restrict__ Wt) {
    int i = blockIdx.x * blockDim.x + threadIdx.x;   // 65536
    int n = i >> 8, k = i & 255;
    Wt[i] = f2b(W[k * 256 + n]);
}

__global__ void k_deg(const int* __restrict__ dst, int* __restrict__ deg) {
    int e = blockIdx.x * 256 + threadIdx.x;
    if (e < N_EDGES) atomicAdd(&deg[dst[e]], 1);
}

__global__ void k_counts(const int* __restrict__ batch, int* __restrict__ counts) {
    int i = blockIdx.x * 256 + threadIdx.x;
    if (i < N_NODES) atomicAdd(&counts[batch[i]], 1);
}

// dinv = rsqrt(in_deg + 1) (self-loop); pdeg = deg rounded up to multiple of 8
__global__ void k_dinv_pdeg(const int* __restrict__ deg, float* __restrict__ dinv,
                            int* __restrict__ pdeg) {
    int i = blockIdx.x * 256 + threadIdx.x;
    if (i < N_NODES) {
        int d = deg[i];
        dinv[i] = rsqrtf((float)d + 1.0f);
        pdeg[i] = (d + 7) & ~7;
    }
}

// single-block exclusive scan of pdeg -> row_ptr[0..n]
__global__ void k_scan(const int* __restrict__ pdeg, int* __restrict__ row_ptr, int n) {
    __shared__ int sh[1024];
    int tid = threadIdx.x;
    int off = 0;
    int nchunk = (n + 1023) >> 10;
    for (int c = 0; c < nchunk; ++c) {
        int i = (c << 10) + tid;
        int v = (i < n) ? pdeg[i] : 0;
        sh[tid] = v;
        __syncthreads();
        for (int s = 1; s < 1024; s <<= 1) {
            int t = (tid >= s) ? sh[tid - s] : 0;
            __syncthreads();
            sh[tid] += t;
            __syncthreads();
        }
        if (i < n) row_ptr[i] = off + sh[tid] - v;   // exclusive
        off += sh[1023];
        __syncthreads();
    }
    if (tid == 0) row_ptr[n] = off;
}

// scatter edges into padded CSR. Pad slots stay (src=0, w=0.0) from the memset.
__global__ void k_fill(const int* __restrict__ src, const int* __restrict__ dst,
                       const int* __restrict__ row_ptr, int* __restrict__ fill,
                       const float* __restrict__ dinv,
                       int* __restrict__ csr_src, float* __restrict__ csr_w) {
    int e = blockIdx.x * 256 + threadIdx.x;
    if (e >= N_EDGES) return;
    int s = src[e], d = dst[e];
    int pos = atomicAdd(&fill[d], 1);
    int idx = row_ptr[d] + pos;
    csr_src[idx] = s;
    csr_w[idx]   = dinv[s] * dinv[d];
}

// ---------------- GEMM: H[M,256] = Xb[M,256] @ W (Wt is W^T, bf16) ----------------
__global__ __launch_bounds__(256) void k_gemm(const ushort* __restrict__ Xb,
                                              const ushort* __restrict__ Wt,
                                              ushort* __restrict__ H) {
    int wave = threadIdx.x >> 6;
    int lane = threadIdx.x & 63;
    int m0 = blockIdx.x * 16;
    int n0 = wave * 64;
    int rl = lane & 15;
    int kq = (lane >> 4) * 8;

    const ushort* aptr = Xb + (size_t)(m0 + rl) * DIM + kq;
    f32x4 acc[4] = {};

#pragma unroll
    for (int kk = 0; kk < 8; ++kk) {
        int k0 = kk * 32;
        bf16x8 a = *(const bf16x8*)(aptr + k0);
#pragma unroll
        for (int nb = 0; nb < 4; ++nb) {
            const ushort* bptr = Wt + (size_t)(n0 + nb * 16 + rl) * DIM + k0 + kq;
            bf16x8 b = *(const bf16x8*)bptr;
            acc[nb] = __builtin_amdgcn_mfma_f32_16x16x32_bf16(a, b, acc[nb], 0, 0, 0);
        }
    }
    int crow = m0 + (lane >> 4) * 4;
    int ccol = n0 + rl;
#pragma unroll
    for (int nb = 0; nb < 4; ++nb)
#pragma unroll
        for (int r = 0; r < 4; ++r)
            H[(size_t)(crow + r) * DIM + ccol + nb * 16] = f2b(acc[nb][r]);
}

// ---------------- aggregation: feature-chunked, L2-resident ----------------
// One pass covers 64 features (128 B/row -> H-chunk 2.5 MB < 4 MB per-XCD L2).
// One wave per node; lanes: j = lane>>3 (edge slot 0..7), b = lane&7 (8 features).
// One gather instruction covers 8 edges x 16 B. CSR/outb use non-temporal
// hints so streams don't evict the resident H chunk.
// mode 0: relu(acc+b) -> outb ; mode 1: relu(prev+acc+b) -> outb
// mode 2: atomicAdd pooled[batch[i]] += acc + b
__global__ __launch_bounds__(256) void k_agg(
    const ushort* __restrict__ H, const int* __restrict__ row_ptr,
    const int* __restrict__ csr_src, const float* __restrict__ csr_w,
    const float* __restrict__ dinv, const float* __restrict__ bias,
    const ushort* __restrict__ prev, ushort* __restrict__ outb,
    float* __restrict__ pooled, const int* __restrict__ batch, int mode, int pass) {
    int wave = threadIdx.x >> 6, lane = threadIdx.x & 63;
    int i = blockIdx.x * 4 + wave;
    if (i >= N_NODES) return;
    int j = lane >> 3;               // edge slot within group of 8
    int b = lane & 7;                // feature sub-chunk
    int fbase = pass * 64 + b * 8;   // 8 features per lane
    const ushort* Hf = H + fbase;

    float di = dinv[i];
    float ws = (j == 0) ? di * di : 0.0f;   // self-loop counted once
    ushort8 sv = *(const ushort8*)(Hf + (size_t)i * DIM);
    float acc[8];
#pragma unroll
    for (int k = 0; k < 8; ++k) acc[k] = ws * b2f(sv[k]);

    int e0 = row_ptr[i], e1 = row_ptr[i + 1];
    for (int e = e0; e < e1; e += 8) {
        int   s = __builtin_nontemporal_load(csr_src + e + j);
        float w = __builtin_nontemporal_load(csr_w + e + j);
        ushort8 v = *(const ushort8*)(Hf + (size_t)s * DIM);
#pragma unroll
        for (int k = 0; k < 8; ++k) acc[k] += w * b2f(v[k]);
    }

    // reduce across the 8 edge-slot groups (lanes with same b)
#pragma unroll
    for (int k = 0; k < 8; ++k) {
        float t = acc[k];
        t += __shfl_xor(t, 8);
        t += __shfl_xor(t, 16);
        t += __shfl_xor(t, 32);
        acc[k] = t;
    }

    const float4 bb0 = *(const float4*)(bias + fbase);
    const float4 bb1 = *(const float4*)(bias + fbase + 4);
    acc[0] += bb0.x; acc[1] += bb0.y; acc[2] += bb0.z; acc[3] += bb0.w;
    acc[4] += bb1.x; acc[5] += bb1.y; acc[6] += bb1.z; acc[7] += bb1.w;

    if (mode == 2) {
        if (j == 0) {
            int g = batch[i];
            float* p = pooled + (size_t)g * DIM + fbase;
#pragma unroll
            for (int k = 0; k < 8; ++k) atomicAdd(p + k, acc[k]);
        }
        return;
    }
    if (mode == 1) {
        ushort8 pv = *(const ushort8*)(prev + (size_t)i * DIM + fbase);
#pragma unroll
        for (int k = 0; k < 8; ++k) acc[k] += b2f(pv[k]);
    }
    if (j == 0) {
        ushort8 o;
#pragma unroll
        for (int k = 0; k < 8; ++k) o[k] = f2b(fmaxf(acc[k], 0.0f));
        __builtin_nontemporal_store(o, (ushort8*)(outb + (size_t)i * DIM + fbase));
    }
}

// ---------------- head: pooled mean -> logits -> log_softmax ----------------
__global__ void k_final(const float* __restrict__ pooled, const int* __restrict__ counts,
                        const float* __restrict__ Wc, const float* __restrict__ bc,
                        float* __restrict__ out) {
    int g = blockIdx.x, lane = threadIdx.x;   // 64 threads = 1 wave
    float inv = 1.0f / fmaxf((float)counts[g], 1.0f);
    const float4 pv = *(const float4*)(pooled + (size_t)g * DIM + lane * 4);
    float p0 = pv.x * inv, p1 = pv.y * inv, p2 = pv.z * inv, p3 = pv.w * inv;
    __shared__ float logits[N_CLASSES];
    int f = lane * 4;
    for (int c = 0; c < N_CLASSES; ++c) {
        float part = p0 * Wc[(f + 0) * N_CLASSES + c] + p1 * Wc[(f + 1) * N_CLASSES + c]
                   + p2 * Wc[(f + 2) * N_CLASSES + c] + p3 * Wc[(f + 3) * N_CLASSES + c];
        for (int s = 32; s > 0; s >>= 1) part += __shfl_down(part, s);
        if (lane == 0) logits[c] = part + bc[c];
    }
    __syncthreads();
    if (lane == 0) {
        float mx = logits[0];
        for (int c = 1; c < N_CLASSES; ++c) mx = fmaxf(mx, logits[c]);
        float se = 0.f;
        for (int c = 0; c < N_CLASSES; ++c) se += expf(logits[c] - mx);
        float lse = mx + logf(se);
        for (int c = 0; c < N_CLASSES; ++c) {
            out[g * N_CLASSES + c] = logits[c];
            out[N_GRAPHS * N_CLASSES + g * N_CLASSES + c] = logits[c] - lse;
        }
    }
}

// ---------------- launch ----------------
extern "C" void kernel_launch(void* const* d_in, const int* in_sizes, int n_in,
                              void* d_out, int out_size, void* d_ws, size_t ws_size,
                              hipStream_t stream) {
    const float* x    = (const float*)d_in[0];
    const int*   ei   = (const int*)d_in[1];
    const int*   src  = ei;
    const int*   dst  = ei + N_EDGES;
    const int*   batch= (const int*)d_in[2];
    const float* W1 = (const float*)d_in[3]; const float* b1 = (const float*)d_in[4];
    const float* W2 = (const float*)d_in[5]; const float* b2 = (const float*)d_in[6];
    const float* W3 = (const float*)d_in[7]; const float* b3 = (const float*)d_in[8];
    const float* Wc = (const float*)d_in[9]; const float* bc = (const float*)d_in[10];
    float* out = (float*)d_out;

    char* ws = (char*)d_ws;
    size_t off = 0;
    auto alloc = [&](size_t bytes) -> char* {
        char* p = ws + off;
        off = (off + bytes + 255) & ~(size_t)255;
        return p;
    };
    // ---- zeroed region (one memset) ----
    int*    deg     = (int*)alloc(N_NODES * 4);
    int*    fill    = (int*)alloc(N_NODES * 4);
    int*    counts  = (int*)alloc(N_GRAPHS * 4);
    float*  pooled  = (float*)alloc(N_GRAPHS * DIM * 4);
    int*    csr_src = (int*)alloc((size_t)CSR_CAP * 4);   // pad slots must be 0
    float*  csr_w   = (float*)alloc((size_t)CSR_CAP * 4); // pad slots must be 0.0f
    size_t  zero_bytes = off;
    // ---- uninitialized scratch ----
    float*  dinv    = (float*)alloc(N_NODES * 4);
    int*    pdeg    = (int*)alloc(N_NODES * 4);
    int*    row_ptr = (int*)alloc((N_NODES + 1) * 4);
    ushort* Wt1     = (ushort*)alloc(65536 * 2);
    ushort* Wt2     = (ushort*)alloc(65536 * 2);
    ushort* Wt3     = (ushort*)alloc(65536 * 2);
    ushort* xb      = (ushort*)alloc((size_t)N_NODES * DIM * 2);
    ushort* h1      = (ushort*)alloc((size_t)N_NODES * DIM * 2);
    ushort* hb      = (ushort*)alloc((size_t)N_NODES * DIM * 2);

    hipMemsetAsync(d_ws, 0, zero_bytes, stream);

    k_convert_x<<<(N_NODES * DIM / 4 + 255) / 256, 256, 0, stream>>>(x, xb, N_NODES * DIM / 4);
    k_wt<<<256, 256, 0, stream>>>(W1, Wt1);
    k_wt<<<256, 256, 0, stream>>>(W2, Wt2);
    k_wt<<<256, 256, 0, stream>>>(W3, Wt3);
    k_deg<<<(N_EDGES + 255) / 256, 256, 0, stream>>>(dst, deg);
    k_counts<<<(N_NODES + 255) / 256, 256, 0, stream>>>(batch, counts);
    k_dinv_pdeg<<<(N_NODES + 255) / 256, 256, 0, stream>>>(deg, dinv, pdeg);
    k_scan<<<1, 1024, 0, stream>>>(pdeg, row_ptr, N_NODES);
    k_fill<<<(N_EDGES + 255) / 256, 256, 0, stream>>>(src, dst, row_ptr, fill, dinv, csr_src, csr_w);

    const int agg_grid = (N_NODES + 3) / 4;

    // conv1: h1 = relu(agg(xb @ W1) + b1)
    k_gemm<<<N_NODES / 16, 256, 0, stream>>>(xb, Wt1, hb);
    for (int p = 0; p < N_PASS; ++p)
        k_agg<<<agg_grid, 256, 0, stream>>>(hb, row_ptr, csr_src, csr_w, dinv, b1,
                                            nullptr, h1, nullptr, nullptr, 0, p);
    // conv2: xb = relu(h1 + agg(h1 @ W2) + b2)
    k_gemm<<<N_NODES / 16, 256, 0, stream>>>(h1, Wt2, hb);
    for (int p = 0; p < N_PASS; ++p)
        k_agg<<<agg_grid, 256, 0, stream>>>(hb, row_ptr, csr_src, csr_w, dinv, b2,
                                            h1, xb, nullptr, nullptr, 1, p);
    // conv3: pooled += agg(xb @ W3) + b3
    k_gemm<<<N_NODES / 16, 256, 0, stream>>>(xb, Wt3, hb);
    for (int p = 0; p < N_PASS; ++p)
        k_agg<<<agg_grid, 256, 0, stream>>>(hb, row_ptr, csr_src, csr_w, dinv, b3,
                                            nullptr, nullptr, pooled, batch, 2, p);

    k_final<<<N_GRAPHS, 64, 0, stream>>>(pooled, counts, Wc, bc, out);
}

// Round 5
// 510.104 us; speedup vs baseline: 2.2625x; 2.2625x over previous
//
#include <hip/hip_runtime.h>
#include <hip/hip_bf16.h>

#define N_NODES   20000
#define N_EDGES   320000
#define DIM       256
#define N_GRAPHS  64
#define N_CLASSES 10
// CSR holds edges + 1 self-loop per node, each row padded to a multiple of 8
#define CSR_CAP   (N_EDGES + 9 * N_NODES)

typedef short  bf16x8 __attribute__((ext_vector_type(8)));
typedef float  f32x4  __attribute__((ext_vector_type(4)));
typedef float  f32x2  __attribute__((ext_vector_type(2)));

__device__ __forceinline__ float b2f(ushort u) {
    return __uint_as_float(((unsigned)u) << 16);
}
__device__ __forceinline__ ushort f2b(float f) {
    unsigned u = __float_as_uint(f);
    u += 0x7FFF + ((u >> 16) & 1);   // round-to-nearest-even
    return (ushort)(u >> 16);
}
// float -> fp8 e4m3 (OCP on gfx950), single value in byte 0
__device__ __forceinline__ unsigned char f2fp8(float f) {
    return (unsigned char)__builtin_amdgcn_cvt_pk_fp8_f32(f, f, 0, false);
}

// ---------------- setup kernels ----------------

__global__ void k_convert_x(const float* __restrict__ x, ushort* __restrict__ xb, int n4) {
    int i = blockIdx.x * blockDim.x + threadIdx.x;
    if (i >= n4) return;
    const float4 v = ((const float4*)x)[i];
    ushort4 o; o.x = f2b(v.x); o.y = f2b(v.y); o.z = f2b(v.z); o.w = f2b(v.w);
    ((ushort4*)xb)[i] = o;
}

// Wt[n*256+k] = bf16(W[k*256+n])
__global__ void k_wt(const float* __restrict__ W, ushort* __restrict__ Wt) {
    int i = blockIdx.x * blockDim.x + threadIdx.x;   // 65536
    int n = i >> 8, k = i & 255;
    Wt[i] = f2b(W[k * 256 + n]);
}

__global__ void k_deg(const int* __restrict__ dst, int* __restrict__ deg) {
    int e = blockIdx.x * 256 + threadIdx.x;
    if (e < N_EDGES) atomicAdd(&deg[dst[e]], 1);
}

__global__ void k_counts(const int* __restrict__ batch, int* __restrict__ counts) {
    int i = blockIdx.x * 256 + threadIdx.x;
    if (i < N_NODES) atomicAdd(&counts[batch[i]], 1);
}

// dinv = rsqrt(in_deg + 1) (self-loop); pdeg = (deg+1 incl self) rounded up to mult of 8
__global__ void k_dinv_pdeg(const int* __restrict__ deg, float* __restrict__ dinv,
                            int* __restrict__ pdeg) {
    int i = blockIdx.x * 256 + threadIdx.x;
    if (i < N_NODES) {
        int d = deg[i];
        dinv[i] = rsqrtf((float)d + 1.0f);
        pdeg[i] = (d + 1 + 7) & ~7;
    }
}

// single-block exclusive scan of pdeg -> row_ptr[0..n]
__global__ void k_scan(const int* __restrict__ pdeg, int* __restrict__ row_ptr, int n) {
    __shared__ int sh[1024];
    int tid = threadIdx.x;
    int off = 0;
    int nchunk = (n + 1023) >> 10;
    for (int c = 0; c < nchunk; ++c) {
        int i = (c << 10) + tid;
        int v = (i < n) ? pdeg[i] : 0;
        sh[tid] = v;
        __syncthreads();
        for (int s = 1; s < 1024; s <<= 1) {
            int t = (tid >= s) ? sh[tid - s] : 0;
            __syncthreads();
            sh[tid] += t;
            __syncthreads();
        }
        if (i < n) row_ptr[i] = off + sh[tid] - v;   // exclusive
        off += sh[1023];
        __syncthreads();
    }
    if (tid == 0) row_ptr[n] = off;
}

// insert self-loop entry (i, dinv_i^2) -- runs before k_fill
__global__ void k_self(const int* __restrict__ row_ptr, int* __restrict__ fill,
                       const float* __restrict__ dinv,
                       int* __restrict__ csr_src, float* __restrict__ csr_w) {
    int i = blockIdx.x * 256 + threadIdx.x;
    if (i >= N_NODES) return;
    int pos = atomicAdd(&fill[i], 1);
    int idx = row_ptr[i] + pos;
    csr_src[idx] = i;
    csr_w[idx]   = dinv[i] * dinv[i];
}

// scatter edges into padded CSR. Pad slots stay (src=0, w=0.0) from the memset.
__global__ void k_fill(const int* __restrict__ src, const int* __restrict__ dst,
                       const int* __restrict__ row_ptr, int* __restrict__ fill,
                       const float* __restrict__ dinv,
                       int* __restrict__ csr_src, float* __restrict__ csr_w) {
    int e = blockIdx.x * 256 + threadIdx.x;
    if (e >= N_EDGES) return;
    int s = src[e], d = dst[e];
    int pos = atomicAdd(&fill[d], 1);
    int idx = row_ptr[d] + pos;
    csr_src[idx] = s;
    csr_w[idx]   = dinv[s] * dinv[d];
}

// ---------------- GEMM: H8[M,256] = fp8(Xb[M,256] @ W) (Wt is W^T, bf16 in) ----------------
// Output ONLY in fp8 e4m3: consumed exclusively by the gather kernel. Halves the
// gather line count (4 lines/row) and makes H ~L2-resident (5.1 MB).
__global__ __launch_bounds__(256) void k_gemm(const ushort* __restrict__ Xb,
                                              const ushort* __restrict__ Wt,
                                              unsigned char* __restrict__ H8) {
    int wave = threadIdx.x >> 6;
    int lane = threadIdx.x & 63;
    int m0 = blockIdx.x * 16;
    int n0 = wave * 64;
    int rl = lane & 15;
    int kq = (lane >> 4) * 8;

    const ushort* aptr = Xb + (size_t)(m0 + rl) * DIM + kq;
    f32x4 acc[4] = {};

#pragma unroll
    for (int kk = 0; kk < 8; ++kk) {
        int k0 = kk * 32;
        bf16x8 a = *(const bf16x8*)(aptr + k0);
#pragma unroll
        for (int nb = 0; nb < 4; ++nb) {
            const ushort* bptr = Wt + (size_t)(n0 + nb * 16 + rl) * DIM + k0 + kq;
            bf16x8 b = *(const bf16x8*)bptr;
            acc[nb] = __builtin_amdgcn_mfma_f32_16x16x32_bf16(a, b, acc[nb], 0, 0, 0);
        }
    }
    int crow = m0 + (lane >> 4) * 4;
    int ccol = n0 + rl;
#pragma unroll
    for (int nb = 0; nb < 4; ++nb)
#pragma unroll
        for (int r = 0; r < 4; ++r)
            H8[(size_t)(crow + r) * DIM + ccol + nb * 16] = f2fp8(acc[nb][r]);
}

// ---------------- aggregation: one wave per node, 4 rows per gather instr ----------------
// Lane layout: j = lane>>4 (edge slot 0..3), b = lane&15 (features b*16..b*16+15).
// One dwordx4 gather = 4 rows x 256 B = 1 KB, 16 lines. Self-loop is a CSR entry.
// Two gathers (8 edges) in flight, index/weight prefetched one iteration ahead.
// R1-R4 lesson: per-CU in-flight-line budget is the ceiling -> fp8 halves lines/row.
// mode 0: relu(acc+b) ; mode 1: relu(prev+acc+b) ; mode 2: atomicAdd pooled
__global__ __launch_bounds__(256) void k_agg(
    const unsigned char* __restrict__ H8, const int* __restrict__ row_ptr,
    const int* __restrict__ csr_src, const float* __restrict__ csr_w,
    const float* __restrict__ bias, const ushort* __restrict__ prev,
    ushort* __restrict__ outb, float* __restrict__ pooled,
    const int* __restrict__ batch, int mode) {
    int wave = threadIdx.x >> 6, lane = threadIdx.x & 63;
    int i = blockIdx.x * 4 + wave;
    if (i >= N_NODES) return;
    int j = lane >> 4;           // edge slot within group of 4
    int b = lane & 15;           // feature block (16 features)
    const unsigned char* Hf = H8 + b * 16;

    float acc[16];
#pragma unroll
    for (int k = 0; k < 16; ++k) acc[k] = 0.0f;

    int e0 = row_ptr[i], e1 = row_ptr[i + 1];   // e1-e0 >= 8, multiple of 8
    int   s0 = csr_src[e0 + j],     s1 = csr_src[e0 + 4 + j];
    float w0 = csr_w [e0 + j],      w1 = csr_w [e0 + 4 + j];
    for (int e = e0; e < e1;) {
        int cs0 = s0, cs1 = s1; float cw0 = w0, cw1 = w1;
        int en = e + 8;
        if (en < e1) {
            s0 = csr_src[en + j]; s1 = csr_src[en + 4 + j];
            w0 = csr_w [en + j]; w1 = csr_w [en + 4 + j];
        }
        uint4 g0 = *(const uint4*)(Hf + (size_t)cs0 * DIM);
        uint4 g1 = *(const uint4*)(Hf + (size_t)cs1 * DIM);
        unsigned d0[4] = {g0.x, g0.y, g0.z, g0.w};
        unsigned d1[4] = {g1.x, g1.y, g1.z, g1.w};
#pragma unroll
        for (int q = 0; q < 4; ++q) {
            f32x2 lo = __builtin_amdgcn_cvt_pk_f32_fp8(d0[q], false);
            f32x2 hi = __builtin_amdgcn_cvt_pk_f32_fp8(d0[q], true);
            acc[q * 4 + 0] += cw0 * lo[0]; acc[q * 4 + 1] += cw0 * lo[1];
            acc[q * 4 + 2] += cw0 * hi[0]; acc[q * 4 + 3] += cw0 * hi[1];
        }
#pragma unroll
        for (int q = 0; q < 4; ++q) {
            f32x2 lo = __builtin_amdgcn_cvt_pk_f32_fp8(d1[q], false);
            f32x2 hi = __builtin_amdgcn_cvt_pk_f32_fp8(d1[q], true);
            acc[q * 4 + 0] += cw1 * lo[0]; acc[q * 4 + 1] += cw1 * lo[1];
            acc[q * 4 + 2] += cw1 * hi[0]; acc[q * 4 + 3] += cw1 * hi[1];
        }
        e = en;
    }

    // reduce over the 4 edge-slot groups (butterfly: all lanes end with the sum)
#pragma unroll
    for (int k = 0; k < 16; ++k) {
        float t = acc[k];
        t += __shfl_xor(t, 16);
        t += __shfl_xor(t, 32);
        acc[k] = t;
    }

    // epilogue: lane handles features fo..fo+3; 64 lanes cover all 256
    int fo = b * 16 + j * 4;
    const float4 bb = *(const float4*)(bias + fo);
    float r0 = acc[j * 4 + 0] + bb.x, r1 = acc[j * 4 + 1] + bb.y;
    float r2 = acc[j * 4 + 2] + bb.z, r3 = acc[j * 4 + 3] + bb.w;

    if (mode == 2) {
        int g = batch[i];
        float* p = pooled + (size_t)g * DIM + fo;
        atomicAdd(p + 0, r0); atomicAdd(p + 1, r1);
        atomicAdd(p + 2, r2); atomicAdd(p + 3, r3);
        return;
    }
    if (mode == 1) {
        ushort4 pv = *(const ushort4*)(prev + (size_t)i * DIM + fo);
        r0 += b2f(pv.x); r1 += b2f(pv.y); r2 += b2f(pv.z); r3 += b2f(pv.w);
    }
    ushort4 o;
    o.x = f2b(fmaxf(r0, 0.f)); o.y = f2b(fmaxf(r1, 0.f));
    o.z = f2b(fmaxf(r2, 0.f)); o.w = f2b(fmaxf(r3, 0.f));
    *(ushort4*)(outb + (size_t)i * DIM + fo) = o;
}

// ---------------- head: pooled mean -> logits -> log_softmax ----------------
__global__ void k_final(const float* __restrict__ pooled, const int* __restrict__ counts,
                        const float* __restrict__ Wc, const float* __restrict__ bc,
                        float* __restrict__ out) {
    int g = blockIdx.x, lane = threadIdx.x;   // 64 threads = 1 wave
    float inv = 1.0f / fmaxf((float)counts[g], 1.0f);
    const float4 pv = *(const float4*)(pooled + (size_t)g * DIM + lane * 4);
    float p0 = pv.x * inv, p1 = pv.y * inv, p2 = pv.z * inv, p3 = pv.w * inv;
    __shared__ float logits[N_CLASSES];
    int f = lane * 4;
    for (int c = 0; c < N_CLASSES; ++c) {
        float part = p0 * Wc[(f + 0) * N_CLASSES + c] + p1 * Wc[(f + 1) * N_CLASSES + c]
                   + p2 * Wc[(f + 2) * N_CLASSES + c] + p3 * Wc[(f + 3) * N_CLASSES + c];
        for (int s = 32; s > 0; s >>= 1) part += __shfl_down(part, s);
        if (lane == 0) logits[c] = part + bc[c];
    }
    __syncthreads();
    if (lane == 0) {
        float mx = logits[0];
        for (int c = 1; c < N_CLASSES; ++c) mx = fmaxf(mx, logits[c]);
        float se = 0.f;
        for (int c = 0; c < N_CLASSES; ++c) se += expf(logits[c] - mx);
        float lse = mx + logf(se);
        for (int c = 0; c < N_CLASSES; ++c) {
            out[g * N_CLASSES + c] = logits[c];
            out[N_GRAPHS * N_CLASSES + g * N_CLASSES + c] = logits[c] - lse;
        }
    }
}

// ---------------- launch ----------------
extern "C" void kernel_launch(void* const* d_in, const int* in_sizes, int n_in,
                              void* d_out, int out_size, void* d_ws, size_t ws_size,
                              hipStream_t stream) {
    const float* x    = (const float*)d_in[0];
    const int*   ei   = (const int*)d_in[1];
    const int*   src  = ei;
    const int*   dst  = ei + N_EDGES;
    const int*   batch= (const int*)d_in[2];
    const float* W1 = (const float*)d_in[3]; const float* b1 = (const float*)d_in[4];
    const float* W2 = (const float*)d_in[5]; const float* b2 = (const float*)d_in[6];
    const float* W3 = (const float*)d_in[7]; const float* b3 = (const float*)d_in[8];
    const float* Wc = (const float*)d_in[9]; const float* bc = (const float*)d_in[10];
    float* out = (float*)d_out;

    char* ws = (char*)d_ws;
    size_t off = 0;
    auto alloc = [&](size_t bytes) -> char* {
        char* p = ws + off;
        off = (off + bytes + 255) & ~(size_t)255;
        return p;
    };
    // ---- zeroed region (one memset) ----
    int*    deg     = (int*)alloc(N_NODES * 4);
    int*    fill    = (int*)alloc(N_NODES * 4);
    int*    counts  = (int*)alloc(N_GRAPHS * 4);
    float*  pooled  = (float*)alloc(N_GRAPHS * DIM * 4);
    int*    csr_src = (int*)alloc((size_t)CSR_CAP * 4);   // pad slots must be 0
    float*  csr_w   = (float*)alloc((size_t)CSR_CAP * 4); // pad slots must be 0.0f
    size_t  zero_bytes = off;
    // ---- uninitialized scratch ----
    float*  dinv    = (float*)alloc(N_NODES * 4);
    int*    pdeg    = (int*)alloc(N_NODES * 4);
    int*    row_ptr = (int*)alloc((N_NODES + 1) * 4);
    ushort* Wt1     = (ushort*)alloc(65536 * 2);
    ushort* Wt2     = (ushort*)alloc(65536 * 2);
    ushort* Wt3     = (ushort*)alloc(65536 * 2);
    ushort* xb      = (ushort*)alloc((size_t)N_NODES * DIM * 2);
    ushort* h1      = (ushort*)alloc((size_t)N_NODES * DIM * 2);
    unsigned char* h8 = (unsigned char*)alloc((size_t)N_NODES * DIM);

    hipMemsetAsync(d_ws, 0, zero_bytes, stream);

    k_convert_x<<<(N_NODES * DIM / 4 + 255) / 256, 256, 0, stream>>>(x, xb, N_NODES * DIM / 4);
    k_wt<<<256, 256, 0, stream>>>(W1, Wt1);
    k_wt<<<256, 256, 0, stream>>>(W2, Wt2);
    k_wt<<<256, 256, 0, stream>>>(W3, Wt3);
    k_deg<<<(N_EDGES + 255) / 256, 256, 0, stream>>>(dst, deg);
    k_counts<<<(N_NODES + 255) / 256, 256, 0, stream>>>(batch, counts);
    k_dinv_pdeg<<<(N_NODES + 255) / 256, 256, 0, stream>>>(deg, dinv, pdeg);
    k_scan<<<1, 1024, 0, stream>>>(pdeg, row_ptr, N_NODES);
    k_self<<<(N_NODES + 255) / 256, 256, 0, stream>>>(row_ptr, fill, dinv, csr_src, csr_w);
    k_fill<<<(N_EDGES + 255) / 256, 256, 0, stream>>>(src, dst, row_ptr, fill, dinv, csr_src, csr_w);

    const int agg_grid = (N_NODES + 3) / 4;

    // conv1: h1 = relu(agg(xb @ W1) + b1)
    k_gemm<<<N_NODES / 16, 256, 0, stream>>>(xb, Wt1, h8);
    k_agg<<<agg_grid, 256, 0, stream>>>(h8, row_ptr, csr_src, csr_w, b1,
                                        nullptr, h1, nullptr, nullptr, 0);
    // conv2: xb = relu(h1 + agg(h1 @ W2) + b2)
    k_gemm<<<N_NODES / 16, 256, 0, stream>>>(h1, Wt2, h8);
    k_agg<<<agg_grid, 256, 0, stream>>>(h8, row_ptr, csr_src, csr_w, b2,
                                        h1, xb, nullptr, nullptr, 1);
    // conv3: pooled += agg(xb @ W3) + b3
    k_gemm<<<N_NODES / 16, 256, 0, stream>>>(xb, Wt3, h8);
    k_agg<<<agg_grid, 256, 0, stream>>>(h8, row_ptr, csr_src, csr_w, b3,
                                        nullptr, nullptr, pooled, batch, 2);

    k_final<<<N_GRAPHS, 64, 0, stream>>>(pooled, counts, Wc, bc, out);
}